// Round 17
// baseline (646.381 us; speedup 1.0000x reference)
//
#include <hip/hip_runtime.h>
#include <hip/hip_bf16.h>
#include <math.h>

#define NB 128
#define NT 20
#define NS 19
#define NR 49
#define NV 10000
#define NE 512
#define NH 512
#define NFD 512
#define NA 256
#define NG 2048
#define NK2 1024   // gates GEMM K after emb-hoist: [ctx | hx]

typedef __bf16 bf16_t;
typedef bf16_t bf16x8 __attribute__((ext_vector_type(8)));
typedef bf16_t bf16x4 __attribute__((ext_vector_type(4)));
typedef float f32x4 __attribute__((ext_vector_type(4)));

__device__ __forceinline__ float sigm(float x) { return 1.f / (1.f + expf(-x)); }

__device__ __forceinline__ void cvt8(bf16_t* d, const float* s) {
    float4 a = *(const float4*)s;
    float4 b = *(const float4*)(s + 4);
    bf16x8 v;
    v[0] = (bf16_t)a.x; v[1] = (bf16_t)a.y; v[2] = (bf16_t)a.z; v[3] = (bf16_t)a.w;
    v[4] = (bf16_t)b.x; v[5] = (bf16_t)b.y; v[6] = (bf16_t)b.z; v[7] = (bf16_t)b.w;
    *(bf16x8*)d = v;
}

// ------------------------------------------------------------------
// k_prep: flat region-dispatch, 8 contiguous dest elems per thread.
// flags region now 19*256 = 4864 uints (608 granules); 6408 blocks.
// ------------------------------------------------------------------
__global__ __launch_bounds__(256) void k_prep(
    const float* __restrict__ fc_W, const float* __restrict__ W_ih,
    const float* __restrict__ W_hh, const float* __restrict__ W_h,
    const float* __restrict__ W_f, const float* __restrict__ features,
    const float* __restrict__ emb, const int* __restrict__ captions,
    const float* __restrict__ b_ih, const float* __restrict__ b_hh,
    const float* __restrict__ b_f, const float* __restrict__ b_h,
    bf16_t* __restrict__ fcWb, bf16_t* __restrict__ Wcat2,
    bf16_t* __restrict__ Wxg, bf16_t* __restrict__ W_hb,
    bf16_t* __restrict__ Wfb, bf16_t* __restrict__ featb,
    bf16_t* __restrict__ linx, float* __restrict__ bias,
    float* __restrict__ bfh, float* __restrict__ hx, float* __restrict__ cx,
    unsigned* __restrict__ flags)
{
    int g = blockIdx.x * 256 + threadIdx.x;
    if (g < 640000) { int idx = g * 8; cvt8(fcWb + idx, fc_W + idx); return; }
    g -= 640000;
    if (g < 262144) {   // Wcat2[2048][1024] = [Wc | Whh], row n'=4h+g
        int idx = g * 8;
        int row = idx >> 10, col = idx & 1023;
        int orig = (row & 3) * NH + (row >> 2);
        const float* src = (col < 512) ? (W_ih + (size_t)orig * 1024 + 512 + col)
                                       : (W_hh + (size_t)orig * 512 + (col - 512));
        cvt8(Wcat2 + idx, src);
        return;
    }
    g -= 262144;
    if (g < 131072) {   // Wxg[2048][512] = x-part, row n'=4h+g
        int idx = g * 8;
        int row = idx >> 9, col = idx & 511;
        int orig = (row & 3) * NH + (row >> 2);
        cvt8(Wxg + idx, W_ih + (size_t)orig * 1024 + col);
        return;
    }
    g -= 131072;
    if (g < 16384) { int idx = g * 8; cvt8(W_hb + idx, W_h + idx); return; }
    g -= 16384;
    if (g < 16384) { int idx = g * 8; cvt8(Wfb + idx, W_f + idx); return; }
    g -= 16384;
    if (g < 401408) { int idx = g * 8; cvt8(featb + idx, features + idx); return; }
    g -= 401408;
    if (g < 155648) {   // linx[2432][512]: emb gather, row = t*128+b
        int idx = g * 8;
        int row = idx >> 9, col = idx & 511;
        int t = row >> 7, b = row & 127;
        int cap = captions[b * NT + t];
        cvt8(linx + idx, emb + (size_t)cap * NE + col);
        return;
    }
    g -= 155648;
    if (g < 256) {      // bias reorder (f32)
        int n0 = g * 8;
        #pragma unroll
        for (int i = 0; i < 8; ++i) {
            int n = n0 + i, h = n >> 2, gg = n & 3;
            int orig = gg * NH + h;
            bias[n] = b_ih[orig] + b_hh[orig];
        }
        return;
    }
    g -= 256;
    if (g < 32) {       // bfh = b_f + b_h (folded into fproj)
        int n0 = g * 8;
        #pragma unroll
        for (int i = 0; i < 8; ++i) bfh[n0 + i] = b_f[n0 + i] + b_h[n0 + i];
        return;
    }
    g -= 32;
    float4 z = make_float4(0.f, 0.f, 0.f, 0.f);
    if (g < 8192) { *(float4*)(hx + g * 8) = z; *(float4*)(hx + g * 8 + 4) = z; return; }
    g -= 8192;
    if (g < 8192) { *(float4*)(cx + g * 8) = z; *(float4*)(cx + g * 8 + 4) = z; return; }
    g -= 8192;
    if (g < 608) {      // per-block flags: 19 steps x 256 blocks
        #pragma unroll
        for (int i = 0; i < 8; ++i) flags[g * 8 + i] = 0u;
    }
}

// ------------------------------------------------------------------
// generic bf16 MFMA GEMM-NT: C[M,N] = A[M,K] @ B[N,K]^T (+bias)
// tile 64x64, BK=64, 4 waves. Cb!=null -> bf16 output, else f32 to Cf.
// ------------------------------------------------------------------
__global__ __launch_bounds__(256) void gemm_bf16_nt(
    const bf16_t* __restrict__ Am, const bf16_t* __restrict__ Bm,
    const float* __restrict__ bias, float* __restrict__ Cf,
    bf16_t* __restrict__ Cb, int M, int N, int K, int ldc)
{
    __shared__ uint4 AsU[512];
    __shared__ uint4 BsU[512];
    int tid = threadIdx.x;
    int m0 = blockIdx.x * 64, n0 = blockIdx.y * 64;
    int nk = K >> 6;

    int rowS = tid >> 3, slotS = tid & 7;
    int wr0 = rowS * 8 + (slotS ^ (rowS & 7));
    int rowS2 = rowS + 32;
    int wr1 = rowS2 * 8 + (slotS ^ (rowS2 & 7));

    const uint4* pA = (const uint4*)(Am + (size_t)(m0 + rowS) * K) + slotS;
    size_t aStep = (size_t)4 * K;
    int nrow0 = n0 + rowS, nrow1 = n0 + rowS2;
    bool bv0 = nrow0 < N, bv1 = nrow1 < N;
    const uint4* pB0 = (const uint4*)(Bm + (size_t)nrow0 * K) + slotS;
    const uint4* pB1 = (const uint4*)(Bm + (size_t)nrow1 * K) + slotS;
    uint4 zz = make_uint4(0, 0, 0, 0);

    int w = tid >> 6, lane = tid & 63;
    int wm = w >> 1, wn = w & 1;
    int lr = lane & 15, lg = lane >> 4;
    int ra[2][2], rb[2][2];
    #pragma unroll
    for (int i = 0; i < 2; ++i)
        #pragma unroll
        for (int kk = 0; kk < 2; ++kk) {
            int rA = wm * 32 + i * 16 + lr;
            int rB = wn * 32 + i * 16 + lr;
            int s = kk * 4 + lg;
            ra[i][kk] = rA * 8 + (s ^ (rA & 7));
            rb[i][kk] = rB * 8 + (s ^ (rB & 7));
        }

    f32x4 acc00 = {}, acc01 = {}, acc10 = {}, acc11 = {};
    uint4 a0 = pA[0], a1 = pA[aStep];
    uint4 b0 = bv0 ? pB0[0] : zz;
    uint4 b1 = bv1 ? pB1[0] : zz;
    pA += 8; pB0 += 8; pB1 += 8;

    #pragma unroll 1
    for (int kt = 0; kt < nk; ++kt) {
        __syncthreads();
        AsU[wr0] = a0; AsU[wr1] = a1;
        BsU[wr0] = b0; BsU[wr1] = b1;
        if (kt + 1 < nk) {
            a0 = pA[0]; a1 = pA[aStep];
            b0 = bv0 ? pB0[0] : zz;
            b1 = bv1 ? pB1[0] : zz;
            pA += 8; pB0 += 8; pB1 += 8;
        }
        __syncthreads();
        const bf16x8* Af = (const bf16x8*)AsU;
        const bf16x8* Bf = (const bf16x8*)BsU;
        #pragma unroll
        for (int kk = 0; kk < 2; ++kk) {
            bf16x8 fa0 = Af[ra[0][kk]], fa1 = Af[ra[1][kk]];
            bf16x8 fb0 = Bf[rb[0][kk]], fb1 = Bf[rb[1][kk]];
            acc00 = __builtin_amdgcn_mfma_f32_16x16x32_bf16(fa0, fb0, acc00, 0, 0, 0);
            acc01 = __builtin_amdgcn_mfma_f32_16x16x32_bf16(fa0, fb1, acc01, 0, 0, 0);
            acc10 = __builtin_amdgcn_mfma_f32_16x16x32_bf16(fa1, fb0, acc10, 0, 0, 0);
            acc11 = __builtin_amdgcn_mfma_f32_16x16x32_bf16(fa1, fb1, acc11, 0, 0, 0);
        }
    }

    f32x4 av[2][2] = {{acc00, acc01}, {acc10, acc11}};
    #pragma unroll
    for (int i = 0; i < 2; ++i) {
        int mbase = m0 + wm * 32 + i * 16 + lg * 4;
        #pragma unroll
        for (int j = 0; j < 2; ++j) {
            int n = n0 + wn * 32 + j * 16 + lr;
            if (n < N) {
                float bz = bias ? bias[n] : 0.f;
                #pragma unroll
                for (int r = 0; r < 4; ++r) {
                    float v = av[i][j][r] + bz;
                    if (Cb) Cb[(size_t)(mbase + r) * ldc + n] = (bf16_t)v;
                    else    Cf[(size_t)(mbase + r) * ldc + n] = v;
                }
            }
        }
    }
}

// ------------------------------------------------------------------
// k_attn (init only, t=0 with hx=0): block b, 512 threads.
// ------------------------------------------------------------------
__global__ __launch_bounds__(512) void k_attn(
    const float* __restrict__ hx, const bf16_t* __restrict__ W_hb,
    const bf16_t* __restrict__ fprojb, const float* __restrict__ v_w,
    const bf16_t* __restrict__ featb, bf16_t* __restrict__ lin)
{
    int b = blockIdx.x;
    int tid = threadIdx.x;
    int w = tid >> 6, lane = tid & 63;
    __shared__ float hxs[NH];
    __shared__ float part[2][NA];
    __shared__ float salpha[64];

    hxs[tid] = hx[b * NH + tid];
    __syncthreads();

    {   // h = hx @ W_h^T
        int a = tid & 255, q = tid >> 8;
        const bf16x8* wrow = (const bf16x8*)(W_hb + (size_t)a * NH + q * 256);
        const float* hq = hxs + q * 256;
        float p = 0.f;
        #pragma unroll
        for (int c = 0; c < 32; ++c) {
            bf16x8 wv = wrow[c];
            int k = c * 8;
            p += hq[k+0]*(float)wv[0] + hq[k+1]*(float)wv[1]
               + hq[k+2]*(float)wv[2] + hq[k+3]*(float)wv[3]
               + hq[k+4]*(float)wv[4] + hq[k+5]*(float)wv[5]
               + hq[k+6]*(float)wv[6] + hq[k+7]*(float)wv[7];
        }
        part[q][a] = p;
    }
    __syncthreads();

    {   // scores: 8 waves strided over r
        for (int r = w; r < NR; r += 8) {
            const bf16_t* fp = fprojb + ((size_t)b * NR + r) * NA;
            float s = 0.f;
            #pragma unroll
            for (int j = 0; j < 4; ++j) {
                int aa = lane + 64 * j;
                float hv = part[0][aa] + part[1][aa];
                s += tanhf(hv + (float)fp[aa]) * v_w[aa];
            }
            #pragma unroll
            for (int off = 32; off; off >>= 1) s += __shfl_xor(s, off);
            if (lane == 0) salpha[r] = s;
        }
    }
    __syncthreads();

    if (tid < 64) {
        float v = (tid < NR) ? salpha[tid] : -INFINITY;
        float m = v;
        #pragma unroll
        for (int off = 32; off; off >>= 1) m = fmaxf(m, __shfl_xor(m, off));
        float e = (tid < NR) ? expf(v - m) : 0.f;
        float ssum = e;
        #pragma unroll
        for (int off = 32; off; off >>= 1) ssum += __shfl_xor(ssum, off);
        if (tid < NR) salpha[tid] = e / ssum;
    }
    __syncthreads();

    {   // context + [ctx | hx] row
        bf16_t* lrow = lin + (size_t)b * NK2;
        float c = 0.f;
        #pragma unroll 7
        for (int r = 0; r < NR; ++r)
            c += salpha[r] * (float)featb[((size_t)b * NR + r) * NFD + tid];
        lrow[tid] = (bf16_t)c;
        lrow[NFD + tid] = (bf16_t)hxs[tid];
    }
}

// ------------------------------------------------------------------
// k_step2: ONE kernel per step, FULL-CHIP 256 blocks x 256 thr.
// Gates GEMM tile 16x64 (ig 0..7, jg 0..31); XCD map jg=4*xcd+(loc&3),
// ig=loc>>2 -> 8 same-jg blocks per XCD (Wcat2 L2 dedup).
// Store-based flag sync (8 groups x 32). Blocks with (loc&3)<2 run
// attention for batch bb = 16*ig + 2*xcd + (loc&3); others exit.
// ------------------------------------------------------------------
__global__ __launch_bounds__(256) void k_step2(
    bf16_t* lin,
    const bf16_t* __restrict__ Wcat2, const bf16_t* __restrict__ pre_x,
    const float* __restrict__ bias, float* hx,
    float* __restrict__ cx, bf16_t* __restrict__ hxAll,
    const bf16_t* __restrict__ W_hb, const bf16_t* __restrict__ fprojb,
    const float* __restrict__ v_w, const bf16_t* __restrict__ featb,
    unsigned* flags, int t, int last)
{
    __shared__ __align__(16) char smem[11584];
    uint4* AsU = (uint4*)smem;          // [128] 16 rows x 8 slots
    uint4* BsU = AsU + 128;             // [512] 64 rows x 8 slots

    int tid = threadIdx.x;
    int xcd = blockIdx.x & 7, loc = blockIdx.x >> 3;   // loc 0..31
    int jg = xcd * 4 + (loc & 3);       // n-tile 0..31
    int ig = loc >> 2;                  // m-tile 0..7
    int m0 = ig * 16, n0 = jg * 64;

    // staging map: 2 B rows + (tid<128: 1 A row) per thread
    int rB0 = tid >> 3, sl = tid & 7;          // B rows 0..31
    int rB1 = rB0 + 32;
    int wrB0 = rB0 * 8 + (sl ^ (rB0 & 7));
    int wrB1 = rB1 * 8 + (sl ^ (rB1 & 7));
    bool hasA = tid < 128;
    int rA_ = tid >> 3;                        // valid for tid<128: 0..15
    int wrA = rA_ * 8 + (sl ^ (rA_ & 7));

    const uint4* pB0 = (const uint4*)(Wcat2 + (size_t)(n0 + rB0) * NK2) + sl;
    const uint4* pB1 = (const uint4*)(Wcat2 + (size_t)(n0 + rB1) * NK2) + sl;
    const uint4* pA  = (const uint4*)(lin + (size_t)(m0 + (hasA ? rA_ : 0)) * NK2) + sl;

    int w = tid >> 6, lane = tid & 63;
    int lr = lane & 15, lg = lane >> 4;
    int raI[2], rbI[2];
    #pragma unroll
    for (int kk = 0; kk < 2; ++kk) {
        int s = kk * 4 + lg;
        int rB = w * 16 + lr;
        raI[kk] = lr * 8 + (s ^ (lr & 7));
        rbI[kk] = rB * 8 + (s ^ (rB & 7));
    }

    // ---------------- phase 1: gates GEMM (16x64, 4 waves) ----------------
    f32x4 acc = {};
    uint4 b0 = pB0[0], b1 = pB1[0], a0 = {};
    if (hasA) a0 = pA[0];
    pB0 += 8; pB1 += 8; pA += 8;

    #pragma unroll 1
    for (int kt = 0; kt < NK2 / 64; ++kt) {
        __syncthreads();
        BsU[wrB0] = b0; BsU[wrB1] = b1;
        if (hasA) AsU[wrA] = a0;
        if (kt + 1 < NK2 / 64) {
            b0 = pB0[0]; b1 = pB1[0]; pB0 += 8; pB1 += 8;
            if (hasA) { a0 = pA[0]; pA += 8; }
        }
        __syncthreads();
        const bf16x8* Af = (const bf16x8*)AsU;
        const bf16x8* Bf = (const bf16x8*)BsU;
        #pragma unroll
        for (int kk = 0; kk < 2; ++kk) {
            bf16x8 fa = Af[raI[kk]];
            bf16x8 fb = Bf[rbI[kk]];
            acc = __builtin_amdgcn_mfma_f32_16x16x32_bf16(fa, fb, acc, 0, 0, 0);
        }
    }

    // ---------------- phase 2: LSTM epilogue ----------------
    __syncthreads();
    float* Ct = (float*)smem;   // [16][65]
    {
        int crow = lg * 4;
        int ccol = w * 16 + lr;
        #pragma unroll
        for (int r = 0; r < 4; ++r)
            Ct[(crow + r) * 65 + ccol] = acc[r];
    }
    __syncthreads();

    {
        int hloc = tid & 15, m = tid >> 4;       // m 0..15
        int bb2 = m0 + m;
        int h = (n0 >> 2) + hloc;
        const float* crow = Ct + m * 65 + hloc * 4;
        const float* brow = bias + n0 + hloc * 4;
        const bf16_t* prow = pre_x + ((size_t)t * NB + bb2) * NG + n0 + hloc * 4;
        float gi = crow[0] + brow[0] + (float)prow[0];
        float gf = crow[1] + brow[1] + (float)prow[1];
        float gg = crow[2] + brow[2] + (float)prow[2];
        float go = crow[3] + brow[3] + (float)prow[3];
        size_t idx = (size_t)bb2 * NH + h;
        float c = sigm(gf) * cx[idx] + sigm(gi) * tanhf(gg);
        float hn = sigm(go) * tanhf(c);
        cx[idx] = c;
        __hip_atomic_store(hx + idx, hn, __ATOMIC_RELAXED,
                           __HIP_MEMORY_SCOPE_AGENT);
        hxAll[((size_t)t * NB + bb2) * NH + h] = (bf16_t)hn;
    }
    if (last) return;

    // -------- phase 3: flag store (all blocks) --------
    __syncthreads();          // drains vmcnt -> hx agent-stores complete
    unsigned* fl = flags + t * 256 + ig * 32;
    if (tid == 0)
        __hip_atomic_store(fl + jg, 1u, __ATOMIC_RELAXED,
                           __HIP_MEMORY_SCOPE_AGENT);

    bool doA = (loc & 3) < 2;
    if (!doA) return;         // half the blocks exit here

    // -------- phase 4: poll all 32 flags of group ig --------
    if (tid < 32) {
        while (__hip_atomic_load(fl + tid, __ATOMIC_RELAXED,
                                 __HIP_MEMORY_SCOPE_AGENT) == 0u)
            __builtin_amdgcn_s_sleep(2);
    }
    __syncthreads();

    // ---------------- phase 5: attention(t+1), batch bb ----------------
    int bb = m0 + xcd * 2 + (loc & 3);     // 16*ig + aslot, aslot 0..15
    float* hxs  = (float*)smem;            // [512]
    float* hatt = hxs + 512;               // [256]
    float* salp = hatt + 256;              // [64]
    float* ctxp = salp + 64;               // [4][64][8] = 2048 f32

    hxs[tid]       = __hip_atomic_load(hx + (size_t)bb * NH + tid,
                                 __ATOMIC_RELAXED, __HIP_MEMORY_SCOPE_AGENT);
    hxs[tid + 256] = __hip_atomic_load(hx + (size_t)bb * NH + tid + 256,
                                 __ATOMIC_RELAXED, __HIP_MEMORY_SCOPE_AGENT);
    __syncthreads();

    {   // hatt[a] = hx[bb] . W_h[a], a = tid, full K=512
        const bf16x8* wrow = (const bf16x8*)(W_hb + (size_t)tid * NH);
        float p = 0.f;
        #pragma unroll
        for (int c = 0; c < 64; ++c) {
            bf16x8 wv = wrow[c];
            int k = c * 8;
            p += hxs[k+0]*(float)wv[0] + hxs[k+1]*(float)wv[1]
               + hxs[k+2]*(float)wv[2] + hxs[k+3]*(float)wv[3]
               + hxs[k+4]*(float)wv[4] + hxs[k+5]*(float)wv[5]
               + hxs[k+6]*(float)wv[6] + hxs[k+7]*(float)wv[7];
        }
        hatt[tid] = p;
    }
    __syncthreads();

    {   // scores: 4 waves strided over r, bf16x4 + float4 loads
        for (int r = w; r < NR; r += 4) {
            bf16x4 fp4 = *(const bf16x4*)(fprojb + ((size_t)bb * NR + r) * NA + lane * 4);
            float4 vw4 = *(const float4*)(v_w + lane * 4);
            const float* hb = hatt + lane * 4;
            float s = tanhf(hb[0] + (float)fp4[0]) * vw4.x
                    + tanhf(hb[1] + (float)fp4[1]) * vw4.y
                    + tanhf(hb[2] + (float)fp4[2]) * vw4.z
                    + tanhf(hb[3] + (float)fp4[3]) * vw4.w;
            #pragma unroll
            for (int off = 32; off; off >>= 1) s += __shfl_xor(s, off);
            if (lane == 0) salp[r] = s;
        }
    }
    __syncthreads();

    if (tid < 64) {   // softmax over R=49
        float v = (tid < NR) ? salp[tid] : -INFINITY;
        float m = v;
        #pragma unroll
        for (int off = 32; off; off >>= 1) m = fmaxf(m, __shfl_xor(m, off));
        float e = (tid < NR) ? expf(v - m) : 0.f;
        float ssum = e;
        #pragma unroll
        for (int off = 32; off; off >>= 1) ssum += __shfl_xor(ssum, off);
        if (tid < NR) salp[tid] = e / ssum;
    }
    __syncthreads();

    {   // context: thread (rg = tid>>6 (0..3), ck = tid&63), bf16x8 chunks
        int ck = tid & 63, rg = tid >> 6;
        float c[8] = {};
        for (int r = rg; r < NR; r += 4) {
            bf16x8 v = *(const bf16x8*)(featb + ((size_t)bb * NR + r) * NFD + ck * 8);
            float al = salp[r];
            #pragma unroll
            for (int jj = 0; jj < 8; ++jj) c[jj] += al * (float)v[jj];
        }
        float* cp = ctxp + (rg * 64 + ck) * 8;
        #pragma unroll
        for (int jj = 0; jj < 8; ++jj) cp[jj] = c[jj];
    }
    __syncthreads();

    {   // reduce 4 r-groups; write lin(t+1) row bb = [ctx | hx], 2 cols/thr
        bf16_t* lrow = lin + (size_t)bb * NK2;
        #pragma unroll
        for (int p2 = 0; p2 < 2; ++p2) {
            int col = tid + p2 * 256;
            float cc = ctxp[col] + ctxp[512 + col]
                     + ctxp[1024 + col] + ctxp[1536 + col];
            lrow[col]       = (bf16_t)cc;
            lrow[512 + col] = (bf16_t)hxs[col];
        }
    }
}

// ------------------------------------------------------------------
// batched logits GEMM: 64x64 tile, XCD-bijective swizzle, LDS-staged
// COALESCED nt epilogue (R16-validated).
// ------------------------------------------------------------------
__global__ __launch_bounds__(256) void k_logits(
    const bf16_t* __restrict__ hxAll, const bf16_t* __restrict__ fcWb,
    const float* __restrict__ fc_b, float* __restrict__ out)
{
    const int NWG = 38 * 157, Q = NWG / 8, RR = NWG % 8;   // 745, 6
    int bid = blockIdx.x;
    int xcd = bid & 7, loc = bid >> 3;
    int swz = (xcd < RR ? xcd * (Q + 1) : RR * (Q + 1) + (xcd - RR) * Q) + loc;
    int m0 = (swz % 38) * 64;
    int n0 = (swz / 38) * 64;

    __shared__ uint4 AsU[512];
    __shared__ uint4 BsU[512];
    int tid = threadIdx.x;

    int rowS = tid >> 3, slotS = tid & 7;
    int wr0 = rowS * 8 + (slotS ^ (rowS & 7));
    int rowS2 = rowS + 32;
    int wr1 = rowS2 * 8 + (slotS ^ (rowS2 & 7));

    const uint4* pA = (const uint4*)(hxAll + (size_t)(m0 + rowS) * NH) + slotS;
    size_t aStep = (size_t)4 * NH;
    int nrow0 = n0 + rowS, nrow1 = n0 + rowS2;
    bool bv0 = nrow0 < NV, bv1 = nrow1 < NV;
    const uint4* pB0 = (const uint4*)(fcWb + (size_t)nrow0 * NH) + slotS;
    const uint4* pB1 = (const uint4*)(fcWb + (size_t)nrow1 * NH) + slotS;
    uint4 zz = make_uint4(0, 0, 0, 0);

    int w = tid >> 6, lane = tid & 63;
    int wm = w >> 1, wn = w & 1;
    int lr = lane & 15, lg = lane >> 4;
    int ra[2][2], rb[2][2];
    #pragma unroll
    for (int i = 0; i < 2; ++i)
        #pragma unroll
        for (int kk = 0; kk < 2; ++kk) {
            int rA = wm * 32 + i * 16 + lr;
            int rB = wn * 32 + i * 16 + lr;
            int s = kk * 4 + lg;
            ra[i][kk] = rA * 8 + (s ^ (rA & 7));
            rb[i][kk] = rB * 8 + (s ^ (rB & 7));
        }

    f32x4 acc00 = {}, acc01 = {}, acc10 = {}, acc11 = {};
    uint4 a0 = pA[0], a1 = pA[aStep];
    uint4 b0 = bv0 ? pB0[0] : zz;
    uint4 b1 = bv1 ? pB1[0] : zz;
    pA += 8; pB0 += 8; pB1 += 8;

    #pragma unroll 1
    for (int kt = 0; kt < NH / 64; ++kt) {
        __syncthreads();
        AsU[wr0] = a0; AsU[wr1] = a1;
        BsU[wr0] = b0; BsU[wr1] = b1;
        if (kt + 1 < NH / 64) {
            a0 = pA[0]; a1 = pA[aStep];
            b0 = bv0 ? pB0[0] : zz;
            b1 = bv1 ? pB1[0] : zz;
            pA += 8; pB0 += 8; pB1 += 8;
        }
        __syncthreads();
        const bf16x8* Af = (const bf16x8*)AsU;
        const bf16x8* Bf = (const bf16x8*)BsU;
        #pragma unroll
        for (int kk = 0; kk < 2; ++kk) {
            bf16x8 fa0 = Af[ra[0][kk]], fa1 = Af[ra[1][kk]];
            bf16x8 fb0 = Bf[rb[0][kk]], fb1 = Bf[rb[1][kk]];
            acc00 = __builtin_amdgcn_mfma_f32_16x16x32_bf16(fa0, fb0, acc00, 0, 0, 0);
            acc01 = __builtin_amdgcn_mfma_f32_16x16x32_bf16(fa0, fb1, acc01, 0, 0, 0);
            acc10 = __builtin_amdgcn_mfma_f32_16x16x32_bf16(fa1, fb0, acc10, 0, 0, 0);
            acc11 = __builtin_amdgcn_mfma_f32_16x16x32_bf16(fa1, fb1, acc11, 0, 0, 0);
        }
    }

    // ---- LDS-staged coalesced nt epilogue: 2 halves of 32 rows ----
    f32x4 av[2][2] = {{acc00, acc01}, {acc10, acc11}};
    float* Ct = (float*)AsU;               // [32][68] f32 = 8704 B
    const int LDC = 68;
    int col4 = (tid & 15) * 4;
    int n = n0 + col4;
    bool nok = n < NV;                     // NV % 4 == 0
    f32x4 bz = {};
    if (nok) bz = *(const f32x4*)(fc_b + n);

    #pragma unroll
    for (int h = 0; h < 2; ++h) {
        __syncthreads();
        if (wm == h) {
            #pragma unroll
            for (int i = 0; i < 2; ++i) {
                int rloc = i * 16 + lg * 4;
                #pragma unroll
                for (int j = 0; j < 2; ++j) {
                    int cloc = wn * 32 + j * 16 + lr;
                    #pragma unroll
                    for (int r = 0; r < 4; ++r)
                        Ct[(rloc + r) * LDC + cloc] = av[i][j][r];
                }
            }
        }
        __syncthreads();
        if (nok) {
            #pragma unroll
            for (int p = 0; p < 2; ++p) {
                int rloc = p * 16 + (tid >> 4);
                int m = m0 + h * 32 + rloc;
                int bb = m & 127, tt = m >> 7;
                f32x4 v = *(const f32x4*)(Ct + rloc * LDC + col4);
                v += bz;
                __builtin_nontemporal_store(
                    v, (f32x4*)(out + ((size_t)bb * NS + tt) * NV + n));
            }
        }
    }
}

// ------------------------------------------------------------------
extern "C" void kernel_launch(void* const* d_in, const int* in_sizes, int n_in,
                              void* d_out, int out_size, void* d_ws, size_t ws_size,
                              hipStream_t stream)
{
    const float* features = (const float*)d_in[0];
    const int*   captions = (const int*)d_in[1];
    const float* emb      = (const float*)d_in[2];
    const float* W_h      = (const float*)d_in[3];
    const float* b_h      = (const float*)d_in[4];
    const float* W_f      = (const float*)d_in[5];
    const float* b_f      = (const float*)d_in[6];
    const float* v_w      = (const float*)d_in[7];
    // d_in[8] = v_b : cancels in softmax
    const float* W_ih     = (const float*)d_in[9];
    const float* W_hh     = (const float*)d_in[10];
    const float* b_ih     = (const float*)d_in[11];
    const float* b_hh     = (const float*)d_in[12];
    const float* fc_W     = (const float*)d_in[13];
    const float* fc_b     = (const float*)d_in[14];
    float* out = (float*)d_out;

    char* base = (char*)d_ws;
    bf16_t* fcWb   = (bf16_t*)base;  base += (size_t)NV * NH * 2;
    bf16_t* Wcat2  = (bf16_t*)base;  base += (size_t)NG * NK2 * 2;
    bf16_t* Wxg    = (bf16_t*)base;  base += (size_t)NG * NE * 2;
    bf16_t* W_hb   = (bf16_t*)base;  base += (size_t)NA * NH * 2;
    bf16_t* Wfb    = (bf16_t*)base;  base += (size_t)NA * NFD * 2;
    bf16_t* featb  = (bf16_t*)base;  base += (size_t)NB * NR * NFD * 2;
    bf16_t* linx   = (bf16_t*)base;  base += (size_t)NS * NB * NE * 2;
    bf16_t* pre_x  = (bf16_t*)base;  base += (size_t)NS * NB * NG * 2;
    bf16_t* lin    = (bf16_t*)base;  base += (size_t)NB * NK2 * 2;
    bf16_t* hxAll  = (bf16_t*)base;  base += (size_t)NS * NB * NH * 2;
    bf16_t* fprojb = (bf16_t*)base;  base += (size_t)NB * NR * NA * 2;
    float*  bias   = (float*)base;   base += (size_t)NG * 4;
    float*  bfh    = (float*)base;   base += (size_t)NA * 4;
    float*  hx     = (float*)base;   base += (size_t)NB * NH * 4;
    float*  cx     = (float*)base;   base += (size_t)NB * NH * 4;
    unsigned* flags = (unsigned*)base; base += (size_t)NS * 256 * 4;
    // total ~42.5 MB

    k_prep<<<dim3(6408), 256, 0, stream>>>(
        fc_W, W_ih, W_hh, W_h, W_f, features, emb, captions, b_ih, b_hh,
        b_f, b_h, fcWb, Wcat2, Wxg, W_hb, Wfb, featb, linx, bias, bfh,
        hx, cx, flags);

    // f_proj = features @ W_f^T + (b_f + b_h) : (6272 x 256), K=512, bf16 out
    gemm_bf16_nt<<<dim3(98, 4), 256, 0, stream>>>(
        featb, Wfb, bfh, (float*)0, fprojb, NB * NR, NA, NFD, NA);

    // pre_x = linx @ Wxg^T : (2432 x 2048), K=512, bf16 out, no bias
    gemm_bf16_nt<<<dim3(38, 32), 256, 0, stream>>>(
        linx, Wxg, (const float*)0, (float*)0, pre_x, NS * NB, NG, NE, NG);

    // lin(0): attention at t=0 with hx = 0
    k_attn<<<dim3(NB), 512, 0, stream>>>(hx, W_hb, fprojb, v_w, featb, lin);

    // 19 fused steps: full-chip 256 blocks x 256 threads
    for (int t = 0; t < NS; ++t) {
        k_step2<<<dim3(256), 256, 0, stream>>>(
            lin, Wcat2, pre_x, bias, hx, cx, hxAll,
            W_hb, fprojb, v_w, featb, flags, t, (t == NS - 1) ? 1 : 0);
    }

    // batched logits: (2432 x 10000), K=512, 64x64 tiles, swizzle + nt-store
    k_logits<<<dim3(38 * 157), 256, 0, stream>>>(hxAll, fcWb, fc_b, out);
}

// Round 18
// 548.775 us; speedup vs baseline: 1.1779x; 1.1779x over previous
//
#include <hip/hip_runtime.h>
#include <hip/hip_bf16.h>
#include <math.h>

#define NB 128
#define NT 20
#define NS 19
#define NR 49
#define NV 10000
#define NE 512
#define NH 512
#define NFD 512
#define NA 256
#define NG 2048
#define NK2 1024   // gates GEMM K after emb-hoist: [ctx | hx]

typedef __bf16 bf16_t;
typedef bf16_t bf16x8 __attribute__((ext_vector_type(8)));
typedef bf16_t bf16x4 __attribute__((ext_vector_type(4)));
typedef float f32x4 __attribute__((ext_vector_type(4)));

__device__ __forceinline__ float sigm(float x) { return 1.f / (1.f + expf(-x)); }

__device__ __forceinline__ void cvt8(bf16_t* d, const float* s) {
    float4 a = *(const float4*)s;
    float4 b = *(const float4*)(s + 4);
    bf16x8 v;
    v[0] = (bf16_t)a.x; v[1] = (bf16_t)a.y; v[2] = (bf16_t)a.z; v[3] = (bf16_t)a.w;
    v[4] = (bf16_t)b.x; v[5] = (bf16_t)b.y; v[6] = (bf16_t)b.z; v[7] = (bf16_t)b.w;
    *(bf16x8*)d = v;
}

// ------------------------------------------------------------------
// k_prep: flat region-dispatch, 8 contiguous dest elems per thread.
// ------------------------------------------------------------------
__global__ __launch_bounds__(256) void k_prep(
    const float* __restrict__ fc_W, const float* __restrict__ W_ih,
    const float* __restrict__ W_hh, const float* __restrict__ W_h,
    const float* __restrict__ W_f, const float* __restrict__ features,
    const float* __restrict__ emb, const int* __restrict__ captions,
    const float* __restrict__ b_ih, const float* __restrict__ b_hh,
    const float* __restrict__ b_f, const float* __restrict__ b_h,
    bf16_t* __restrict__ fcWb, bf16_t* __restrict__ Wcat2,
    bf16_t* __restrict__ Wxg, bf16_t* __restrict__ W_hb,
    bf16_t* __restrict__ Wfb, bf16_t* __restrict__ featb,
    bf16_t* __restrict__ linx, float* __restrict__ bias,
    float* __restrict__ bfh, float* __restrict__ hx, float* __restrict__ cx,
    unsigned* __restrict__ flags)
{
    int g = blockIdx.x * 256 + threadIdx.x;
    if (g < 640000) { int idx = g * 8; cvt8(fcWb + idx, fc_W + idx); return; }
    g -= 640000;
    if (g < 262144) {   // Wcat2[2048][1024] = [Wc | Whh], row n'=4h+g
        int idx = g * 8;
        int row = idx >> 10, col = idx & 1023;
        int orig = (row & 3) * NH + (row >> 2);
        const float* src = (col < 512) ? (W_ih + (size_t)orig * 1024 + 512 + col)
                                       : (W_hh + (size_t)orig * 512 + (col - 512));
        cvt8(Wcat2 + idx, src);
        return;
    }
    g -= 262144;
    if (g < 131072) {   // Wxg[2048][512] = x-part, row n'=4h+g
        int idx = g * 8;
        int row = idx >> 9, col = idx & 511;
        int orig = (row & 3) * NH + (row >> 2);
        cvt8(Wxg + idx, W_ih + (size_t)orig * 1024 + col);
        return;
    }
    g -= 131072;
    if (g < 16384) { int idx = g * 8; cvt8(W_hb + idx, W_h + idx); return; }
    g -= 16384;
    if (g < 16384) { int idx = g * 8; cvt8(Wfb + idx, W_f + idx); return; }
    g -= 16384;
    if (g < 401408) { int idx = g * 8; cvt8(featb + idx, features + idx); return; }
    g -= 401408;
    if (g < 155648) {   // linx[2432][512]: emb gather, row = t*128+b
        int idx = g * 8;
        int row = idx >> 9, col = idx & 511;
        int t = row >> 7, b = row & 127;
        int cap = captions[b * NT + t];
        cvt8(linx + idx, emb + (size_t)cap * NE + col);
        return;
    }
    g -= 155648;
    if (g < 256) {      // bias reorder (f32)
        int n0 = g * 8;
        #pragma unroll
        for (int i = 0; i < 8; ++i) {
            int n = n0 + i, h = n >> 2, gg = n & 3;
            int orig = gg * NH + h;
            bias[n] = b_ih[orig] + b_hh[orig];
        }
        return;
    }
    g -= 256;
    if (g < 32) {       // bfh = b_f + b_h (folded into fproj)
        int n0 = g * 8;
        #pragma unroll
        for (int i = 0; i < 8; ++i) bfh[n0 + i] = b_f[n0 + i] + b_h[n0 + i];
        return;
    }
    g -= 32;
    float4 z = make_float4(0.f, 0.f, 0.f, 0.f);
    if (g < 8192) { *(float4*)(hx + g * 8) = z; *(float4*)(hx + g * 8 + 4) = z; return; }
    g -= 8192;
    if (g < 8192) { *(float4*)(cx + g * 8) = z; *(float4*)(cx + g * 8 + 4) = z; return; }
    g -= 8192;
    if (g < 304) {      // per-block flags: 19 steps x 128 blocks = 2432 uints
        #pragma unroll
        for (int i = 0; i < 8; ++i) flags[g * 8 + i] = 0u;
    }
}

// ------------------------------------------------------------------
// generic bf16 MFMA GEMM-NT: C[M,N] = A[M,K] @ B[N,K]^T (+bias)
// tile 64x64, BK=64, 4 waves. Cb!=null -> bf16 output, else f32 to Cf.
// ------------------------------------------------------------------
__global__ __launch_bounds__(256) void gemm_bf16_nt(
    const bf16_t* __restrict__ Am, const bf16_t* __restrict__ Bm,
    const float* __restrict__ bias, float* __restrict__ Cf,
    bf16_t* __restrict__ Cb, int M, int N, int K, int ldc)
{
    __shared__ uint4 AsU[512];
    __shared__ uint4 BsU[512];
    int tid = threadIdx.x;
    int m0 = blockIdx.x * 64, n0 = blockIdx.y * 64;
    int nk = K >> 6;

    int rowS = tid >> 3, slotS = tid & 7;
    int wr0 = rowS * 8 + (slotS ^ (rowS & 7));
    int rowS2 = rowS + 32;
    int wr1 = rowS2 * 8 + (slotS ^ (rowS2 & 7));

    const uint4* pA = (const uint4*)(Am + (size_t)(m0 + rowS) * K) + slotS;
    size_t aStep = (size_t)4 * K;
    int nrow0 = n0 + rowS, nrow1 = n0 + rowS2;
    bool bv0 = nrow0 < N, bv1 = nrow1 < N;
    const uint4* pB0 = (const uint4*)(Bm + (size_t)nrow0 * K) + slotS;
    const uint4* pB1 = (const uint4*)(Bm + (size_t)nrow1 * K) + slotS;
    uint4 zz = make_uint4(0, 0, 0, 0);

    int w = tid >> 6, lane = tid & 63;
    int wm = w >> 1, wn = w & 1;
    int lr = lane & 15, lg = lane >> 4;
    int ra[2][2], rb[2][2];
    #pragma unroll
    for (int i = 0; i < 2; ++i)
        #pragma unroll
        for (int kk = 0; kk < 2; ++kk) {
            int rA = wm * 32 + i * 16 + lr;
            int rB = wn * 32 + i * 16 + lr;
            int s = kk * 4 + lg;
            ra[i][kk] = rA * 8 + (s ^ (rA & 7));
            rb[i][kk] = rB * 8 + (s ^ (rB & 7));
        }

    f32x4 acc00 = {}, acc01 = {}, acc10 = {}, acc11 = {};
    uint4 a0 = pA[0], a1 = pA[aStep];
    uint4 b0 = bv0 ? pB0[0] : zz;
    uint4 b1 = bv1 ? pB1[0] : zz;
    pA += 8; pB0 += 8; pB1 += 8;

    #pragma unroll 1
    for (int kt = 0; kt < nk; ++kt) {
        __syncthreads();
        AsU[wr0] = a0; AsU[wr1] = a1;
        BsU[wr0] = b0; BsU[wr1] = b1;
        if (kt + 1 < nk) {
            a0 = pA[0]; a1 = pA[aStep];
            b0 = bv0 ? pB0[0] : zz;
            b1 = bv1 ? pB1[0] : zz;
            pA += 8; pB0 += 8; pB1 += 8;
        }
        __syncthreads();
        const bf16x8* Af = (const bf16x8*)AsU;
        const bf16x8* Bf = (const bf16x8*)BsU;
        #pragma unroll
        for (int kk = 0; kk < 2; ++kk) {
            bf16x8 fa0 = Af[ra[0][kk]], fa1 = Af[ra[1][kk]];
            bf16x8 fb0 = Bf[rb[0][kk]], fb1 = Bf[rb[1][kk]];
            acc00 = __builtin_amdgcn_mfma_f32_16x16x32_bf16(fa0, fb0, acc00, 0, 0, 0);
            acc01 = __builtin_amdgcn_mfma_f32_16x16x32_bf16(fa0, fb1, acc01, 0, 0, 0);
            acc10 = __builtin_amdgcn_mfma_f32_16x16x32_bf16(fa1, fb0, acc10, 0, 0, 0);
            acc11 = __builtin_amdgcn_mfma_f32_16x16x32_bf16(fa1, fb1, acc11, 0, 0, 0);
        }
    }

    f32x4 av[2][2] = {{acc00, acc01}, {acc10, acc11}};
    #pragma unroll
    for (int i = 0; i < 2; ++i) {
        int mbase = m0 + wm * 32 + i * 16 + lg * 4;
        #pragma unroll
        for (int j = 0; j < 2; ++j) {
            int n = n0 + wn * 32 + j * 16 + lr;
            if (n < N) {
                float bz = bias ? bias[n] : 0.f;
                #pragma unroll
                for (int r = 0; r < 4; ++r) {
                    float v = av[i][j][r] + bz;
                    if (Cb) Cb[(size_t)(mbase + r) * ldc + n] = (bf16_t)v;
                    else    Cf[(size_t)(mbase + r) * ldc + n] = v;
                }
            }
        }
    }
}

// ------------------------------------------------------------------
// k_attn (init only, t=0 with hx=0): block b, 512 threads.
// ------------------------------------------------------------------
__global__ __launch_bounds__(512) void k_attn(
    const float* __restrict__ hx, const bf16_t* __restrict__ W_hb,
    const bf16_t* __restrict__ fprojb, const float* __restrict__ v_w,
    const bf16_t* __restrict__ featb, bf16_t* __restrict__ lin)
{
    int b = blockIdx.x;
    int tid = threadIdx.x;
    int w = tid >> 6, lane = tid & 63;
    __shared__ float hxs[NH];
    __shared__ float part[2][NA];
    __shared__ float salpha[64];

    hxs[tid] = hx[b * NH + tid];
    __syncthreads();

    {   // h = hx @ W_h^T
        int a = tid & 255, q = tid >> 8;
        const bf16x8* wrow = (const bf16x8*)(W_hb + (size_t)a * NH + q * 256);
        const float* hq = hxs + q * 256;
        float p = 0.f;
        #pragma unroll
        for (int c = 0; c < 32; ++c) {
            bf16x8 wv = wrow[c];
            int k = c * 8;
            p += hq[k+0]*(float)wv[0] + hq[k+1]*(float)wv[1]
               + hq[k+2]*(float)wv[2] + hq[k+3]*(float)wv[3]
               + hq[k+4]*(float)wv[4] + hq[k+5]*(float)wv[5]
               + hq[k+6]*(float)wv[6] + hq[k+7]*(float)wv[7];
        }
        part[q][a] = p;
    }
    __syncthreads();

    {   // scores: 8 waves strided over r
        for (int r = w; r < NR; r += 8) {
            const bf16_t* fp = fprojb + ((size_t)b * NR + r) * NA;
            float s = 0.f;
            #pragma unroll
            for (int j = 0; j < 4; ++j) {
                int aa = lane + 64 * j;
                float hv = part[0][aa] + part[1][aa];
                s += tanhf(hv + (float)fp[aa]) * v_w[aa];
            }
            #pragma unroll
            for (int off = 32; off; off >>= 1) s += __shfl_xor(s, off);
            if (lane == 0) salpha[r] = s;
        }
    }
    __syncthreads();

    if (tid < 64) {
        float v = (tid < NR) ? salpha[tid] : -INFINITY;
        float m = v;
        #pragma unroll
        for (int off = 32; off; off >>= 1) m = fmaxf(m, __shfl_xor(m, off));
        float e = (tid < NR) ? expf(v - m) : 0.f;
        float ssum = e;
        #pragma unroll
        for (int off = 32; off; off >>= 1) ssum += __shfl_xor(ssum, off);
        if (tid < NR) salpha[tid] = e / ssum;
    }
    __syncthreads();

    {   // context + [ctx | hx] row
        bf16_t* lrow = lin + (size_t)b * NK2;
        float c = 0.f;
        #pragma unroll 7
        for (int r = 0; r < NR; ++r)
            c += salpha[r] * (float)featb[((size_t)b * NR + r) * NFD + tid];
        lrow[tid] = (bf16_t)c;
        lrow[NFD + tid] = (bf16_t)hxs[tid];
    }
}

// ------------------------------------------------------------------
// k_fused (R12 exact): ONE kernel per step. 128 blocks x 512 thr.
// XCD-aware mapping; store-based flag sync; agent-scope hx handoff.
// ------------------------------------------------------------------
__global__ __launch_bounds__(512) void k_fused(
    bf16_t* lin,
    const bf16_t* __restrict__ Wcat2, const bf16_t* __restrict__ pre_x,
    const float* __restrict__ bias, float* hx,
    float* __restrict__ cx, bf16_t* __restrict__ hxAll,
    const bf16_t* __restrict__ W_hb, const bf16_t* __restrict__ fprojb,
    const float* __restrict__ v_w, const bf16_t* __restrict__ featb,
    unsigned* flags, int t, int last)
{
    __shared__ __align__(16) char smem[20736];
    uint4* AsU = (uint4*)smem;          // [256]  32 rows x 8 slots
    uint4* BsU = AsU + 256;             // [512]  64 rows x 8 slots

    int tid = threadIdx.x;
    int xcd = blockIdx.x & 7, loc = blockIdx.x >> 3;
    int jg = xcd * 4 + (loc & 3);       // n-tile 0..31
    int ig = loc >> 2;                  // m-tile 0..3
    int m0 = ig * 32, n0 = jg * 64;

    int rowS = tid >> 3, slotS = tid & 7;     // rowS 0..63
    int wrB = rowS * 8 + (slotS ^ (rowS & 7));
    bool hasA = rowS < 32;
    int arow = hasA ? (m0 + rowS) : m0;

    const uint4* pB = (const uint4*)(Wcat2 + (size_t)(n0 + rowS) * NK2) + slotS;
    const uint4* pA = (const uint4*)(lin + (size_t)arow * NK2) + slotS;

    int w = tid >> 6, lane = tid & 63;
    int wm = w & 1, wn = w >> 1;        // wave tile (wm*16, wn*16) of 32x64
    int lr = lane & 15, lg = lane >> 4;
    int raI[2], rbI[2];
    #pragma unroll
    for (int kk = 0; kk < 2; ++kk) {
        int s = kk * 4 + lg;
        int rA = wm * 16 + lr;
        int rB = wn * 16 + lr;
        raI[kk] = rA * 8 + (s ^ (rA & 7));
        rbI[kk] = rB * 8 + (s ^ (rB & 7));
    }

    // ---------------- phase 1: gates GEMM ----------------
    f32x4 acc = {};
    uint4 aR = {}, bR = pB[0];
    if (hasA) aR = pA[0];
    pB += 8; pA += 8;

    #pragma unroll 1
    for (int kt = 0; kt < NK2 / 64; ++kt) {
        __syncthreads();
        BsU[wrB] = bR;
        if (hasA) AsU[wrB] = aR;
        if (kt + 1 < NK2 / 64) {
            bR = pB[0]; pB += 8;
            if (hasA) { aR = pA[0]; pA += 8; }
        }
        __syncthreads();
        const bf16x8* Af = (const bf16x8*)AsU;
        const bf16x8* Bf = (const bf16x8*)BsU;
        #pragma unroll
        for (int kk = 0; kk < 2; ++kk) {
            bf16x8 fa = Af[raI[kk]];
            bf16x8 fb = Bf[rbI[kk]];
            acc = __builtin_amdgcn_mfma_f32_16x16x32_bf16(fa, fb, acc, 0, 0, 0);
        }
    }

    // ---------------- phase 2: LSTM epilogue ----------------
    __syncthreads();
    float* Ct = (float*)smem;   // [32][65]
    {
        int crow = wm * 16 + lg * 4;
        int ccol = wn * 16 + lr;
        #pragma unroll
        for (int r = 0; r < 4; ++r)
            Ct[(crow + r) * 65 + ccol] = acc[r];
    }
    __syncthreads();

    {
        int hloc = tid & 15, m = tid >> 4;       // m 0..31
        int bb2 = m0 + m;
        int h = (n0 >> 2) + hloc;
        const float* crow = Ct + m * 65 + hloc * 4;
        const float* brow = bias + n0 + hloc * 4;
        const bf16_t* prow = pre_x + ((size_t)t * NB + bb2) * NG + n0 + hloc * 4;
        float gi = crow[0] + brow[0] + (float)prow[0];
        float gf = crow[1] + brow[1] + (float)prow[1];
        float gg = crow[2] + brow[2] + (float)prow[2];
        float go = crow[3] + brow[3] + (float)prow[3];
        size_t idx = (size_t)bb2 * NH + h;
        float c = sigm(gf) * cx[idx] + sigm(gi) * tanhf(gg);
        float hn = sigm(go) * tanhf(c);
        cx[idx] = c;
        __hip_atomic_store(hx + idx, hn, __ATOMIC_RELAXED,
                           __HIP_MEMORY_SCOPE_AGENT);
        hxAll[((size_t)t * NB + bb2) * NH + h] = (bf16_t)hn;
    }
    if (last) return;

    // -------- phase 3/4: store-based group-ig flag sync (no RMW) --------
    __syncthreads();          // drains vmcnt -> this block's hx stores complete
    {
        unsigned* fl = flags + t * 128 + ig * 32;
        if (tid == 0)
            __hip_atomic_store(fl + jg, 1u, __ATOMIC_RELAXED,
                               __HIP_MEMORY_SCOPE_AGENT);
        if (tid < 32) {
            while (__hip_atomic_load(fl + tid, __ATOMIC_RELAXED,
                                     __HIP_MEMORY_SCOPE_AGENT) == 0u)
                __builtin_amdgcn_s_sleep(2);
        }
    }
    __syncthreads();

    // ---------------- phase 5: attention(t+1) for batch bb ----------------
    int bb = m0 + jg;                      // 32*ig + jg
    float* hxs  = (float*)smem;            // [512]
    float* part = hxs + 512;               // [2*256]
    float* salp = part + 512;              // [64]
    float* ctxp = salp + 64;               // [8][64][8] f32 = 16 KB

    hxs[tid] = __hip_atomic_load(hx + (size_t)bb * NH + tid,
                                 __ATOMIC_RELAXED, __HIP_MEMORY_SCOPE_AGENT);
    __syncthreads();

    {   // hatt partials: (q = tid>>8, a = tid&255), half-K dot
        int a = tid & 255, q = tid >> 8;
        const bf16x8* wrow = (const bf16x8*)(W_hb + (size_t)a * NH + q * 256);
        const float* hq = hxs + q * 256;
        float p = 0.f;
        #pragma unroll
        for (int c = 0; c < 32; ++c) {
            bf16x8 wv = wrow[c];
            int k = c * 8;
            p += hq[k+0]*(float)wv[0] + hq[k+1]*(float)wv[1]
               + hq[k+2]*(float)wv[2] + hq[k+3]*(float)wv[3]
               + hq[k+4]*(float)wv[4] + hq[k+5]*(float)wv[5]
               + hq[k+6]*(float)wv[6] + hq[k+7]*(float)wv[7];
        }
        part[q * 256 + a] = p;
    }
    __syncthreads();
    if (tid < 256) part[tid] += part[256 + tid];
    __syncthreads();

    {   // scores: 8 waves strided over r, bf16x4 + float4 loads
        for (int r = w; r < NR; r += 8) {
            bf16x4 fp4 = *(const bf16x4*)(fprojb + ((size_t)bb * NR + r) * NA + lane * 4);
            float4 vw4 = *(const float4*)(v_w + lane * 4);
            const float* hb = part + lane * 4;
            float s = tanhf(hb[0] + (float)fp4[0]) * vw4.x
                    + tanhf(hb[1] + (float)fp4[1]) * vw4.y
                    + tanhf(hb[2] + (float)fp4[2]) * vw4.z
                    + tanhf(hb[3] + (float)fp4[3]) * vw4.w;
            #pragma unroll
            for (int off = 32; off; off >>= 1) s += __shfl_xor(s, off);
            if (lane == 0) salp[r] = s;
        }
    }
    __syncthreads();

    if (tid < 64) {   // softmax over R=49
        float v = (tid < NR) ? salp[tid] : -INFINITY;
        float m = v;
        #pragma unroll
        for (int off = 32; off; off >>= 1) m = fmaxf(m, __shfl_xor(m, off));
        float e = (tid < NR) ? expf(v - m) : 0.f;
        float ssum = e;
        #pragma unroll
        for (int off = 32; off; off >>= 1) ssum += __shfl_xor(ssum, off);
        if (tid < NR) salp[tid] = e / ssum;
    }
    __syncthreads();

    {   // context: thread (rg = tid>>6, ck = tid&63) does bf16x8 chunks
        int ck = tid & 63, rg = tid >> 6;
        float c[8] = {};
        for (int r = rg; r < NR; r += 8) {
            bf16x8 v = *(const bf16x8*)(featb + ((size_t)bb * NR + r) * NFD + ck * 8);
            float al = salp[r];
            #pragma unroll
            for (int jj = 0; jj < 8; ++jj) c[jj] += al * (float)v[jj];
        }
        float* cp = ctxp + (rg * 64 + ck) * 8;
        #pragma unroll
        for (int jj = 0; jj < 8; ++jj) cp[jj] = c[jj];
    }
    __syncthreads();

    {   // reduce 8 r-groups; write lin(t+1) row bb = [ctx | hx]
        float cc = 0.f;
        #pragma unroll
        for (int rg = 0; rg < 8; ++rg) cc += ctxp[rg * 512 + tid];
        bf16_t* lrow = lin + (size_t)bb * NK2;
        lrow[tid]       = (bf16_t)cc;
        lrow[512 + tid] = (bf16_t)hxs[tid];
    }
}

// ------------------------------------------------------------------
// batched logits GEMM: 64x64 tile, XCD-bijective swizzle, LDS-staged
// COALESCED nt epilogue (R16-validated).
// ------------------------------------------------------------------
__global__ __launch_bounds__(256) void k_logits(
    const bf16_t* __restrict__ hxAll, const bf16_t* __restrict__ fcWb,
    const float* __restrict__ fc_b, float* __restrict__ out)
{
    const int NWG = 38 * 157, Q = NWG / 8, RR = NWG % 8;   // 745, 6
    int bid = blockIdx.x;
    int xcd = bid & 7, loc = bid >> 3;
    int swz = (xcd < RR ? xcd * (Q + 1) : RR * (Q + 1) + (xcd - RR) * Q) + loc;
    int m0 = (swz % 38) * 64;
    int n0 = (swz / 38) * 64;

    __shared__ uint4 AsU[512];
    __shared__ uint4 BsU[512];
    int tid = threadIdx.x;

    int rowS = tid >> 3, slotS = tid & 7;
    int wr0 = rowS * 8 + (slotS ^ (rowS & 7));
    int rowS2 = rowS + 32;
    int wr1 = rowS2 * 8 + (slotS ^ (rowS2 & 7));

    const uint4* pA = (const uint4*)(hxAll + (size_t)(m0 + rowS) * NH) + slotS;
    size_t aStep = (size_t)4 * NH;
    int nrow0 = n0 + rowS, nrow1 = n0 + rowS2;
    bool bv0 = nrow0 < NV, bv1 = nrow1 < NV;
    const uint4* pB0 = (const uint4*)(fcWb + (size_t)nrow0 * NH) + slotS;
    const uint4* pB1 = (const uint4*)(fcWb + (size_t)nrow1 * NH) + slotS;
    uint4 zz = make_uint4(0, 0, 0, 0);

    int w = tid >> 6, lane = tid & 63;
    int wm = w >> 1, wn = w & 1;
    int lr = lane & 15, lg = lane >> 4;
    int ra[2][2], rb[2][2];
    #pragma unroll
    for (int i = 0; i < 2; ++i)
        #pragma unroll
        for (int kk = 0; kk < 2; ++kk) {
            int rA = wm * 32 + i * 16 + lr;
            int rB = wn * 32 + i * 16 + lr;
            int s = kk * 4 + lg;
            ra[i][kk] = rA * 8 + (s ^ (rA & 7));
            rb[i][kk] = rB * 8 + (s ^ (rB & 7));
        }

    f32x4 acc00 = {}, acc01 = {}, acc10 = {}, acc11 = {};
    uint4 a0 = pA[0], a1 = pA[aStep];
    uint4 b0 = bv0 ? pB0[0] : zz;
    uint4 b1 = bv1 ? pB1[0] : zz;
    pA += 8; pB0 += 8; pB1 += 8;

    #pragma unroll 1
    for (int kt = 0; kt < NH / 64; ++kt) {
        __syncthreads();
        AsU[wr0] = a0; AsU[wr1] = a1;
        BsU[wr0] = b0; BsU[wr1] = b1;
        if (kt + 1 < NH / 64) {
            a0 = pA[0]; a1 = pA[aStep];
            b0 = bv0 ? pB0[0] : zz;
            b1 = bv1 ? pB1[0] : zz;
            pA += 8; pB0 += 8; pB1 += 8;
        }
        __syncthreads();
        const bf16x8* Af = (const bf16x8*)AsU;
        const bf16x8* Bf = (const bf16x8*)BsU;
        #pragma unroll
        for (int kk = 0; kk < 2; ++kk) {
            bf16x8 fa0 = Af[ra[0][kk]], fa1 = Af[ra[1][kk]];
            bf16x8 fb0 = Bf[rb[0][kk]], fb1 = Bf[rb[1][kk]];
            acc00 = __builtin_amdgcn_mfma_f32_16x16x32_bf16(fa0, fb0, acc00, 0, 0, 0);
            acc01 = __builtin_amdgcn_mfma_f32_16x16x32_bf16(fa0, fb1, acc01, 0, 0, 0);
            acc10 = __builtin_amdgcn_mfma_f32_16x16x32_bf16(fa1, fb0, acc10, 0, 0, 0);
            acc11 = __builtin_amdgcn_mfma_f32_16x16x32_bf16(fa1, fb1, acc11, 0, 0, 0);
        }
    }

    // ---- LDS-staged coalesced nt epilogue: 2 halves of 32 rows ----
    f32x4 av[2][2] = {{acc00, acc01}, {acc10, acc11}};
    float* Ct = (float*)AsU;               // [32][68] f32 = 8704 B
    const int LDC = 68;
    int col4 = (tid & 15) * 4;
    int n = n0 + col4;
    bool nok = n < NV;                     // NV % 4 == 0
    f32x4 bz = {};
    if (nok) bz = *(const f32x4*)(fc_b + n);

    #pragma unroll
    for (int h = 0; h < 2; ++h) {
        __syncthreads();
        if (wm == h) {
            #pragma unroll
            for (int i = 0; i < 2; ++i) {
                int rloc = i * 16 + lg * 4;
                #pragma unroll
                for (int j = 0; j < 2; ++j) {
                    int cloc = wn * 32 + j * 16 + lr;
                    #pragma unroll
                    for (int r = 0; r < 4; ++r)
                        Ct[(rloc + r) * LDC + cloc] = av[i][j][r];
                }
            }
        }
        __syncthreads();
        if (nok) {
            #pragma unroll
            for (int p = 0; p < 2; ++p) {
                int rloc = p * 16 + (tid >> 4);
                int m = m0 + h * 32 + rloc;
                int bb = m & 127, tt = m >> 7;
                f32x4 v = *(const f32x4*)(Ct + rloc * LDC + col4);
                v += bz;
                __builtin_nontemporal_store(
                    v, (f32x4*)(out + ((size_t)bb * NS + tt) * NV + n));
            }
        }
    }
}

// ------------------------------------------------------------------
extern "C" void kernel_launch(void* const* d_in, const int* in_sizes, int n_in,
                              void* d_out, int out_size, void* d_ws, size_t ws_size,
                              hipStream_t stream)
{
    const float* features = (const float*)d_in[0];
    const int*   captions = (const int*)d_in[1];
    const float* emb      = (const float*)d_in[2];
    const float* W_h      = (const float*)d_in[3];
    const float* b_h      = (const float*)d_in[4];
    const float* W_f      = (const float*)d_in[5];
    const float* b_f      = (const float*)d_in[6];
    const float* v_w      = (const float*)d_in[7];
    // d_in[8] = v_b : cancels in softmax
    const float* W_ih     = (const float*)d_in[9];
    const float* W_hh     = (const float*)d_in[10];
    const float* b_ih     = (const float*)d_in[11];
    const float* b_hh     = (const float*)d_in[12];
    const float* fc_W     = (const float*)d_in[13];
    const float* fc_b     = (const float*)d_in[14];
    float* out = (float*)d_out;

    char* base = (char*)d_ws;
    bf16_t* fcWb   = (bf16_t*)base;  base += (size_t)NV * NH * 2;
    bf16_t* Wcat2  = (bf16_t*)base;  base += (size_t)NG * NK2 * 2;
    bf16_t* Wxg    = (bf16_t*)base;  base += (size_t)NG * NE * 2;
    bf16_t* W_hb   = (bf16_t*)base;  base += (size_t)NA * NH * 2;
    bf16_t* Wfb    = (bf16_t*)base;  base += (size_t)NA * NFD * 2;
    bf16_t* featb  = (bf16_t*)base;  base += (size_t)NB * NR * NFD * 2;
    bf16_t* linx   = (bf16_t*)base;  base += (size_t)NS * NB * NE * 2;
    bf16_t* pre_x  = (bf16_t*)base;  base += (size_t)NS * NB * NG * 2;
    bf16_t* lin    = (bf16_t*)base;  base += (size_t)NB * NK2 * 2;
    bf16_t* hxAll  = (bf16_t*)base;  base += (size_t)NS * NB * NH * 2;
    bf16_t* fprojb = (bf16_t*)base;  base += (size_t)NB * NR * NA * 2;
    float*  bias   = (float*)base;   base += (size_t)NG * 4;
    float*  bfh    = (float*)base;   base += (size_t)NA * 4;
    float*  hx     = (float*)base;   base += (size_t)NB * NH * 4;
    float*  cx     = (float*)base;   base += (size_t)NB * NH * 4;
    unsigned* flags = (unsigned*)base; base += (size_t)NS * 128 * 4;
    // total ~42.5 MB

    k_prep<<<dim3(6407), 256, 0, stream>>>(
        fc_W, W_ih, W_hh, W_h, W_f, features, emb, captions, b_ih, b_hh,
        b_f, b_h, fcWb, Wcat2, Wxg, W_hb, Wfb, featb, linx, bias, bfh,
        hx, cx, flags);

    // f_proj = features @ W_f^T + (b_f + b_h) : (6272 x 256), K=512, bf16 out
    gemm_bf16_nt<<<dim3(98, 4), 256, 0, stream>>>(
        featb, Wfb, bfh, (float*)0, fprojb, NB * NR, NA, NFD, NA);

    // pre_x = linx @ Wxg^T : (2432 x 2048), K=512, bf16 out, no bias
    gemm_bf16_nt<<<dim3(38, 32), 256, 0, stream>>>(
        linx, Wxg, (const float*)0, (float*)0, pre_x, NS * NB, NG, NE, NG);

    // lin(0): attention at t=0 with hx = 0
    k_attn<<<dim3(NB), 512, 0, stream>>>(hx, W_hb, fprojb, v_w, featb, lin);

    // 19 fused steps: gates+LSTM then in-kernel attention(t+1)
    for (int t = 0; t < NS; ++t) {
        k_fused<<<dim3(128), 512, 0, stream>>>(
            lin, Wcat2, pre_x, bias, hx, cx, hxAll,
            W_hb, fprojb, v_w, featb, flags, t, (t == NS - 1) ? 1 : 0);
    }

    // batched logits: (2432 x 10000), K=512, 64x64 tiles, swizzle + nt-store
    k_logits<<<dim3(38 * 157), 256, 0, stream>>>(hxAll, fcWb, fc_b, out);
}